// Round 1
// baseline (17.699 us; speedup 1.0000x reference)
//
#include <hip/hip_runtime.h>

#define MEM_SIZE (1 << 20)
#define NUM_WRITES 64

// Kernel A: copy memory -> new_memory (d_out + 64), vectorized float4.
__global__ void copy_mem_kernel(const float4* __restrict__ src,
                                float4* __restrict__ dst, int n4) {
    int i = blockIdx.x * blockDim.x + threadIdx.x;
    if (i < n4) dst[i] = src[i];
}

// Kernel B: 64 threads. Gather reads from ORIGINAL memory, then apply the 64
// sequential soft writes (numerically exact delta-softmax => w = enable) to
// the copied memory. Duplicate addresses compose in time order; only the
// first-occurrence thread of each unique address computes & stores.
__global__ void patch_kernel(const float* __restrict__ memory,
                             const int* __restrict__ read_addrs,
                             const int* __restrict__ write_addrs,
                             const float* __restrict__ write_values,
                             const float* __restrict__ write_enable,
                             float* __restrict__ out_reads,
                             float* __restrict__ out_mem) {
    int t = threadIdx.x;  // 0..63

    // Batched reads: softmax is a numerical delta at the exact address.
    int ra = read_addrs[t];
    out_reads[t] = memory[ra];

    // Writes.
    __shared__ int   s_addr[NUM_WRITES];
    __shared__ float s_val[NUM_WRITES];
    __shared__ float s_en[NUM_WRITES];
    int a = write_addrs[t];
    s_addr[t] = a;
    s_val[t]  = write_values[t];
    s_en[t]   = write_enable[t];
    __syncthreads();

    // First-occurrence check (handles duplicate write addresses).
    bool first = true;
    for (int j = 0; j < t; ++j) {
        if (s_addr[j] == a) { first = false; break; }
    }
    if (first) {
        float m = memory[a];
        // Compose all writes to this address in time order:
        // m = m*(1-w) + v*w, w = softmax(s)*en == en in fp32 (tail ~1e-20).
        for (int j = 0; j < NUM_WRITES; ++j) {
            if (s_addr[j] == a) {
                float w = s_en[j];
                m = m * (1.0f - w) + s_val[j] * w;
            }
        }
        out_mem[a] = m;  // runs after copy kernel (stream ordered) -> wins
    }
}

extern "C" void kernel_launch(void* const* d_in, const int* in_sizes, int n_in,
                              void* d_out, int out_size, void* d_ws, size_t ws_size,
                              hipStream_t stream) {
    const float* memory       = (const float*)d_in[0];
    const int*   read_addrs   = (const int*)d_in[1];
    const int*   write_addrs  = (const int*)d_in[2];
    const float* write_values = (const float*)d_in[3];
    const float* write_enable = (const float*)d_in[4];

    float* out_reads = (float*)d_out;            // [64]
    float* out_mem   = (float*)d_out + 64;       // [MEM_SIZE]

    // Kernel A: copy memory into out_mem. out_mem is 64 floats = 256 B past
    // d_out, so float4 alignment holds.
    int n4 = MEM_SIZE / 4;
    int block = 256;
    int grid = (n4 + block - 1) / block;
    copy_mem_kernel<<<grid, block, 0, stream>>>(
        (const float4*)memory, (float4*)out_mem, n4);

    // Kernel B: reads + sequential write patches.
    patch_kernel<<<1, NUM_WRITES, 0, stream>>>(
        memory, read_addrs, write_addrs, write_values, write_enable,
        out_reads, out_mem);
}

// Round 2
// 10.696 us; speedup vs baseline: 1.6547x; 1.6547x over previous
//
#include <hip/hip_runtime.h>

#define MEM_SIZE (1 << 20)
#define N4 (MEM_SIZE / 4)
#define NW 64

// Single fused kernel:
//  - grid of 1024 blocks x 256 threads, each thread copies one float4 of
//    memory -> out_mem, patching inline any of the 64 soft-writes that land
//    in its float4 (applied in time order j=0..63 => duplicates compose).
//  - block 0 threads 0..63 also gather the 64 reads from ORIGINAL memory.
// Numerics: softmax over binary-encoded scores is an exact fp32 delta at the
// matching address (gap = 200/sqrt(20) => tail weights ~1e-20 underflow vs 1),
// so read = memory[addr] and write weight w = enable. Verified absmax 0.0.
__global__ __launch_bounds__(256) void fused_kernel(
    const float* __restrict__ memory,
    const int* __restrict__ read_addrs,
    const int* __restrict__ write_addrs,
    const float* __restrict__ write_values,
    const float* __restrict__ write_enable,
    float* __restrict__ out_reads,
    float* __restrict__ out_mem)
{
    __shared__ int   s_idx[NW];   // float4 index of each write
    __shared__ int   s_lane[NW];  // component 0..3 within the float4
    __shared__ float s_val[NW];
    __shared__ float s_en[NW];

    const int t = threadIdx.x;
    const int i = blockIdx.x * 256 + t;       // this thread's float4 index
    const int blockStart = blockIdx.x * 256;  // block's float4 range start

    int pred = 0;
    if (t < NW) {
        int a = write_addrs[t];
        int idx4 = a >> 2;
        s_idx[t]  = idx4;
        s_lane[t] = a & 3;
        s_val[t]  = write_values[t];
        s_en[t]   = write_enable[t];
        pred = ((unsigned)(idx4 - blockStart) < 256u);
    }

    // Reads: independent gathers from original memory (never modified).
    if (blockIdx.x == 0 && t < NW) {
        out_reads[t] = memory[read_addrs[t]];
    }

    // Barrier doubles as "any patch in this block's range?" reduction.
    const int any = __syncthreads_or(pred);

    float4 v = ((const float4*)memory)[i];

    if (any) {
        // Rare path (<7% of blocks): apply matching patches in time order.
        for (int j = 0; j < NW; ++j) {
            if (s_idx[j] == i) {
                const float w   = s_en[j];
                const float val = s_val[j];
                const int   l   = s_lane[j];
                float cur = (l == 0) ? v.x : (l == 1) ? v.y : (l == 2) ? v.z : v.w;
                cur = cur * (1.0f - w) + val * w;
                if      (l == 0) v.x = cur;
                else if (l == 1) v.y = cur;
                else if (l == 2) v.z = cur;
                else             v.w = cur;
            }
        }
    }

    ((float4*)out_mem)[i] = v;
}

extern "C" void kernel_launch(void* const* d_in, const int* in_sizes, int n_in,
                              void* d_out, int out_size, void* d_ws, size_t ws_size,
                              hipStream_t stream) {
    const float* memory       = (const float*)d_in[0];
    const int*   read_addrs   = (const int*)d_in[1];
    const int*   write_addrs  = (const int*)d_in[2];
    const float* write_values = (const float*)d_in[3];
    const float* write_enable = (const float*)d_in[4];

    float* out_reads = (float*)d_out;        // [64]
    float* out_mem   = (float*)d_out + 64;   // [MEM_SIZE], 256B offset keeps float4 alignment

    fused_kernel<<<N4 / 256, 256, 0, stream>>>(
        memory, read_addrs, write_addrs, write_values, write_enable,
        out_reads, out_mem);
}